// Round 2
// baseline (159.876 us; speedup 1.0000x reference)
//
#include <hip/hip_runtime.h>

// qpNet: h = x @ W^T + b ; z = max(-h, -1/eps), eps=1e-3  => z = max(-h, -1000)
// x: [B,5] f32, W: [5,5] f32, b: [5] f32, out z: [B,5] f32. B = 4194304.
// Memory-bound streaming kernel: 4 rows (= 5 float4) per thread, grid-stride.

#define ROWS_PER_THREAD 4   // 4 rows * 5 floats = 20 floats = 5 float4
#define BLOCK 256

__global__ __launch_bounds__(BLOCK) void qpnet_kernel(
    const float* __restrict__ x,
    const float* __restrict__ W,
    const float* __restrict__ bfc,
    float* __restrict__ out,
    int n_groups)   // number of 4-row groups
{
    // Load W (5x5) and bias into registers; uniform across all lanes, L1-cached.
    float w[5][5];
    float bias[5];
#pragma unroll
    for (int j = 0; j < 5; ++j) {
        bias[j] = bfc[j];
#pragma unroll
        for (int i = 0; i < 5; ++i) {
            w[j][i] = W[j * 5 + i];
        }
    }

    const int stride = gridDim.x * BLOCK;
    for (int t = blockIdx.x * BLOCK + threadIdx.x; t < n_groups; t += stride) {
        const float4* __restrict__ xin  = reinterpret_cast<const float4*>(x) + (size_t)t * 5;
        float4* __restrict__       zout = reinterpret_cast<float4*>(out)     + (size_t)t * 5;

        // 5 contiguous float4 loads = 20 floats = 4 rows of 5.
        float v[20];
        *reinterpret_cast<float4*>(&v[0])  = xin[0];
        *reinterpret_cast<float4*>(&v[4])  = xin[1];
        *reinterpret_cast<float4*>(&v[8])  = xin[2];
        *reinterpret_cast<float4*>(&v[12]) = xin[3];
        *reinterpret_cast<float4*>(&v[16]) = xin[4];

        float o[20];
#pragma unroll
        for (int k = 0; k < 4; ++k) {
#pragma unroll
            for (int j = 0; j < 5; ++j) {
                float h = bias[j];
#pragma unroll
                for (int i = 0; i < 5; ++i) {
                    h = fmaf(v[k * 5 + i], w[j][i], h);
                }
                o[k * 5 + j] = fmaxf(-h, -1000.0f);
            }
        }

        zout[0] = *reinterpret_cast<float4*>(&o[0]);
        zout[1] = *reinterpret_cast<float4*>(&o[4]);
        zout[2] = *reinterpret_cast<float4*>(&o[8]);
        zout[3] = *reinterpret_cast<float4*>(&o[12]);
        zout[4] = *reinterpret_cast<float4*>(&o[16]);
    }
}

extern "C" void kernel_launch(void* const* d_in, const int* in_sizes, int n_in,
                              void* d_out, int out_size, void* d_ws, size_t ws_size,
                              hipStream_t stream) {
    const float* x   = (const float*)d_in[0];   // [B,5]
    const float* W   = (const float*)d_in[1];   // [5,5]
    const float* bfc = (const float*)d_in[2];   // [5]
    float* out = (float*)d_out;                 // [B,5]

    int B = in_sizes[0] / 5;                    // 4194304
    int n_groups = B / ROWS_PER_THREAD;         // 1048576 (B divisible by 4)
    int grid = (n_groups + BLOCK - 1) / BLOCK;  // 4096 blocks

    qpnet_kernel<<<grid, BLOCK, 0, stream>>>(x, W, bfc, out, n_groups);
}

// Round 3
// 153.754 us; speedup vs baseline: 1.0398x; 1.0398x over previous
//
#include <hip/hip_runtime.h>

// qpNet: h = x @ W^T + b ; z = max(-h, -1000). x:[B,5] f32, W:[5,5], b:[5].
// B = 4194304. Memory-bound. Round-2 lesson: direct per-row access = 80 B
// lane stride -> ~4x transaction count, capped at ~2.9 TB/s effective.
// Fix: LDS-staged transpose so ALL global traffic is stride-1 coalesced
// float4; the row-gather happens in LDS with a rotate swizzle.

#define BLOCK 256
#define F4_PER_THREAD 5                     // 5 float4 = 20 floats = 4 rows
#define TILE_F4 (BLOCK * F4_PER_THREAD)     // 1280 float4 / block (20 KB)
#define LDS_WORDS (BLOCK * 20)              // 5120 f32, no pad (swizzled)

// Swizzled LDS word address for float4 #p (0..4) of thread-region g (0..255).
// Rotate-by-(g%5) keeps 16 B alignment (all offsets multiples of 4 words)
// while breaking the 20-word stride's bank alignment.
__device__ __forceinline__ int lds_addr(int g, int p) {
    int r = g % 5;
    int s = p + r;
    if (s >= 5) s -= 5;
    return g * 20 + 4 * s;
}

__global__ __launch_bounds__(BLOCK) void qpnet_kernel(
    const float* __restrict__ x,
    const float* __restrict__ W,
    const float* __restrict__ bfc,
    float* __restrict__ out,
    int total_f4)   // total float4 count = B*5/4
{
    __shared__ __align__(16) float lds[LDS_WORDS];

    // 5x5 weights + bias in registers (uniform, scalar-cached).
    float w[5][5];
    float bias[5];
#pragma unroll
    for (int j = 0; j < 5; ++j) {
        bias[j] = bfc[j];
#pragma unroll
        for (int i = 0; i < 5; ++i) w[j][i] = W[j * 5 + i];
    }

    const int tid = threadIdx.x;
    const int tile_base = blockIdx.x * TILE_F4;      // fits int (max ~5.2M)
    const float4* __restrict__ xin  = reinterpret_cast<const float4*>(x);
    float4* __restrict__       zout = reinterpret_cast<float4*>(out);

    // ---- stage in: coalesced global float4 -> swizzled LDS ----
#pragma unroll
    for (int k = 0; k < F4_PER_THREAD; ++k) {
        int f = k * BLOCK + tid;                     // tile-local float4 idx
        int gf = tile_base + f;
        if (gf < total_f4) {
            float4 val = xin[gf];
            int g = f / 5, p = f - g * 5;
            *reinterpret_cast<float4*>(&lds[lds_addr(g, p)]) = val;
        }
    }
    __syncthreads();

    // ---- compute: thread t consumes its own 20-float region ----
    float v[20];
    {
        int r = tid % 5;
#pragma unroll
        for (int p = 0; p < 5; ++p) {
            int s = p + r; if (s >= 5) s -= 5;
            *reinterpret_cast<float4*>(&v[4 * p]) =
                *reinterpret_cast<const float4*>(&lds[tid * 20 + 4 * s]);
        }
    }
#pragma unroll
    for (int k = 0; k < 4; ++k) {                    // 4 rows
        float t0, t1, t2, t3, t4;
        t0 = bias[0]; t1 = bias[1]; t2 = bias[2]; t3 = bias[3]; t4 = bias[4];
#pragma unroll
        for (int i = 0; i < 5; ++i) {
            float xv = v[k * 5 + i];
            t0 = fmaf(xv, w[0][i], t0);
            t1 = fmaf(xv, w[1][i], t1);
            t2 = fmaf(xv, w[2][i], t2);
            t3 = fmaf(xv, w[3][i], t3);
            t4 = fmaf(xv, w[4][i], t4);
        }
        v[k * 5 + 0] = fmaxf(-t0, -1000.0f);         // overwrite in place
        v[k * 5 + 1] = fmaxf(-t1, -1000.0f);
        v[k * 5 + 2] = fmaxf(-t2, -1000.0f);
        v[k * 5 + 3] = fmaxf(-t3, -1000.0f);
        v[k * 5 + 4] = fmaxf(-t4, -1000.0f);
    }
    // write results back to own region (no barrier needed: own words only)
    {
        int r = tid % 5;
#pragma unroll
        for (int p = 0; p < 5; ++p) {
            int s = p + r; if (s >= 5) s -= 5;
            *reinterpret_cast<float4*>(&lds[tid * 20 + 4 * s]) =
                *reinterpret_cast<const float4*>(&v[4 * p]);
        }
    }
    __syncthreads();

    // ---- stage out: swizzled LDS -> coalesced global float4 ----
#pragma unroll
    for (int k = 0; k < F4_PER_THREAD; ++k) {
        int f = k * BLOCK + tid;
        int gf = tile_base + f;
        if (gf < total_f4) {
            int g = f / 5, p = f - g * 5;
            zout[gf] = *reinterpret_cast<const float4*>(&lds[lds_addr(g, p)]);
        }
    }
}

extern "C" void kernel_launch(void* const* d_in, const int* in_sizes, int n_in,
                              void* d_out, int out_size, void* d_ws, size_t ws_size,
                              hipStream_t stream) {
    const float* x   = (const float*)d_in[0];   // [B,5]
    const float* W   = (const float*)d_in[1];   // [5,5]
    const float* bfc = (const float*)d_in[2];   // [5]
    float* out = (float*)d_out;                 // [B,5]

    int total_f4 = in_sizes[0] / 4;             // 5,242,880 (B*5 divisible by 4)
    int grid = (total_f4 + TILE_F4 - 1) / TILE_F4;  // 4096

    qpnet_kernel<<<grid, BLOCK, 0, stream>>>(x, W, bfc, out, total_f4);
}